// Round 1
// 2170.007 us; speedup vs baseline: 1.4972x; 1.4972x over previous
//
#include <hip/hip_runtime.h>
#include <math.h>

#define B_ 32
#define T_ 64
#define V_ 32000
#define D_ 512
#define E_ 1024
#define H_ 1024
#define G4_ 4096   // 4*H
#define ED_ 1536   // E + D
#define M_ 2048    // T*B

typedef unsigned short u16;

using bf16x8 = __attribute__((ext_vector_type(8))) short;
using f32x4  = __attribute__((ext_vector_type(4))) float;

// fp32 -> bf16 (RNE) and back, bit-level (values here are finite/normal)
__device__ __forceinline__ u16 f2bf(float x) {
  unsigned u = __float_as_uint(x);
  u += 0x7FFFu + ((u >> 16) & 1u);
  return (u16)(u >> 16);
}
__device__ __forceinline__ float bf2f(u16 h) {
  return __uint_as_float(((unsigned)h) << 16);
}

// ---------------------------------------------------------------------------
// K0: build X[m][c] = concat(encoder[b], emb[gt[b][t]]),  m = t*32 + b
// ---------------------------------------------------------------------------
__global__ __launch_bounds__(256) void build_x(const float* __restrict__ enc,
                                               const int* __restrict__ gt,
                                               const float* __restrict__ emb,
                                               float* __restrict__ X) {
  int m = blockIdx.x;                        // 0..2047
  int col = blockIdx.y * 256 + threadIdx.x;  // 0..1535
  int t = m >> 5, b = m & 31;
  float v;
  if (col < E_) {
    v = enc[b * E_ + col];
  } else {
    int gid = gt[b * T_ + t];
    v = emb[(size_t)gid * D_ + (col - E_)];
  }
  X[(size_t)m * ED_ + col] = v;
}

__global__ __launch_bounds__(256) void bias_sum_k(const float* __restrict__ a,
                                                  const float* __restrict__ b,
                                                  float* __restrict__ o) {
  int i = blockIdx.x * 256 + threadIdx.x;
  if (i < G4_) o[i] = a[i] + b[i];
}

// ---------------------------------------------------------------------------
// Generic fp32 GEMM:  C[M][N] = A[M][K] * B[N][K]^T + bias[N]
// 128x128 tile, 256 threads, 8x8 per thread, BK=16. (kept for the K1 preact GEMM)
// ---------------------------------------------------------------------------
__global__ __launch_bounds__(256) void gemm_abt(const float* __restrict__ A,
                                                const float* __restrict__ Bm,
                                                const float* __restrict__ bias,
                                                float* __restrict__ C,
                                                int M, int N, int K) {
  __shared__ __align__(16) float As[16][128];   // [k][m]
  __shared__ __align__(16) float Bs[16][128];   // [k][n]
  const int tid = threadIdx.x;
  const int bm = blockIdx.y * 128;
  const int bn = blockIdx.x * 128;
  const int tx = tid & 15, ty = tid >> 4;
  const int lr = tid >> 1;            // 0..127 tile row
  const int lk = (tid & 1) * 8;       // 0 or 8
  const float* Ap = A + (size_t)(bm + lr) * K + lk;
  const float* Bp = Bm + (size_t)(bn + lr) * K + lk;

  float acc[8][8];
#pragma unroll
  for (int i = 0; i < 8; ++i)
#pragma unroll
    for (int j = 0; j < 8; ++j) acc[i][j] = 0.f;

  for (int k0 = 0; k0 < K; k0 += 16) {
    const float4 av0 = *(const float4*)(Ap + k0);
    const float4 av1 = *(const float4*)(Ap + k0 + 4);
    const float4 bv0 = *(const float4*)(Bp + k0);
    const float4 bv1 = *(const float4*)(Bp + k0 + 4);
    __syncthreads();   // previous iter's reads done before overwrite
    As[lk + 0][lr] = av0.x; As[lk + 1][lr] = av0.y;
    As[lk + 2][lr] = av0.z; As[lk + 3][lr] = av0.w;
    As[lk + 4][lr] = av1.x; As[lk + 5][lr] = av1.y;
    As[lk + 6][lr] = av1.z; As[lk + 7][lr] = av1.w;
    Bs[lk + 0][lr] = bv0.x; Bs[lk + 1][lr] = bv0.y;
    Bs[lk + 2][lr] = bv0.z; Bs[lk + 3][lr] = bv0.w;
    Bs[lk + 4][lr] = bv1.x; Bs[lk + 5][lr] = bv1.y;
    Bs[lk + 6][lr] = bv1.z; Bs[lk + 7][lr] = bv1.w;
    __syncthreads();
#pragma unroll
    for (int k = 0; k < 16; ++k) {
      const float4 a0 = *(const float4*)&As[k][ty * 8];
      const float4 a1 = *(const float4*)&As[k][ty * 8 + 4];
      const float4 b0 = *(const float4*)&Bs[k][tx * 8];
      const float4 b1 = *(const float4*)&Bs[k][tx * 8 + 4];
      const float a[8] = {a0.x, a0.y, a0.z, a0.w, a1.x, a1.y, a1.z, a1.w};
      const float b[8] = {b0.x, b0.y, b0.z, b0.w, b1.x, b1.y, b1.z, b1.w};
#pragma unroll
      for (int i = 0; i < 8; ++i)
#pragma unroll
        for (int j = 0; j < 8; ++j)
          acc[i][j] = fmaf(a[i], b[j], acc[i][j]);
    }
  }

#pragma unroll
  for (int i = 0; i < 8; ++i) {
    const int row = bm + ty * 8 + i;
    float* Cp = C + (size_t)row * N + bn + tx * 8;
    float o[8];
#pragma unroll
    for (int j = 0; j < 8; ++j) o[j] = acc[i][j] + bias[bn + tx * 8 + j];
    *(float4*)(Cp)     = make_float4(o[0], o[1], o[2], o[3]);
    *(float4*)(Cp + 4) = make_float4(o[4], o[5], o[6], o[7]);
  }
}

// ---------------------------------------------------------------------------
// MFMA GEMM, bf16x3 emulated-fp32:
//   C[M][N] = (Ahi+Alo)[M][K] * Bf[N][K]^T + bias[N]
// A is pre-split bf16 (hi/lo), B is fp32 converted to hi/lo during staging.
// 128x128 tile, BK=32, 256 threads = 4 waves (2x2), wave tile 64x64,
// mfma_f32_16x16x32_bf16, 3 MFMAs per fragment pair (drop lo*lo).
// LDS tiles [row 0..127][k 0..31] padded to stride 40 bf16 (80 B = 5*16 B):
// frag reads stay 16B-aligned, banks 2-way (free, m136).
// ---------------------------------------------------------------------------
__global__ __launch_bounds__(256) void gemm_bf16x3(
    const u16* __restrict__ Ahi, const u16* __restrict__ Alo,
    const float* __restrict__ Bf, const float* __restrict__ bias,
    float* __restrict__ C, int M, int N, int K) {
  __shared__ __align__(16) u16 Ah_s[128 * 40];
  __shared__ __align__(16) u16 Al_s[128 * 40];
  __shared__ __align__(16) u16 Bh_s[128 * 40];
  __shared__ __align__(16) u16 Bl_s[128 * 40];

  const int tid = threadIdx.x;
  const int bn = blockIdx.x * 128;
  const int bm = blockIdx.y * 128;
  const int wave = tid >> 6, lane = tid & 63;
  const int wm = wave >> 1, wn = wave & 1;      // wave grid 2x2
  const int r16 = lane & 15, kj = lane >> 4;    // frag row/col, k-block

  // A staging: thread -> (row tid>>1, k-half (tid&1)*16), two 16B loads per matrix
  const int ar = tid >> 1;
  const int ak = (tid & 1) * 16;
  const u16* gAh = Ahi + (size_t)(bm + ar) * K + ak;
  const u16* gAl = Alo + (size_t)(bm + ar) * K + ak;

  // B staging: thread -> (row (tid>>3)+32p, k-chunk (tid&7)*4), coalesced 128B/8 lanes
  const int br = tid >> 3;         // 0..31
  const int bk = (tid & 7) * 4;    // float offset in k
  const float* gB = Bf + (size_t)(bn + br) * K + bk;

  f32x4 acc[4][4];
#pragma unroll
  for (int i = 0; i < 4; ++i)
#pragma unroll
    for (int j = 0; j < 4; ++j) acc[i][j] = (f32x4){0.f, 0.f, 0.f, 0.f};

  // prologue: prefetch tile k0=0
  uint4 pa0 = *(const uint4*)(gAh);
  uint4 pa1 = *(const uint4*)(gAh + 8);
  uint4 pl0 = *(const uint4*)(gAl);
  uint4 pl1 = *(const uint4*)(gAl + 8);
  float4 pb[4];
#pragma unroll
  for (int p = 0; p < 4; ++p) pb[p] = *(const float4*)(gB + (size_t)(p * 32) * K);

  const int abase = (wm * 64 + r16) * 40 + kj * 8;
  const int bbase = (wn * 64 + r16) * 40 + kj * 8;

  for (int k0 = 0; k0 < K; k0 += 32) {
    // convert staged B fp32 -> hi/lo bf16 (VALU; overlaps other blocks' MFMA)
    union { u16 u[4]; uint2 v; } ph[4], pl[4];
#pragma unroll
    for (int p = 0; p < 4; ++p) {
      const float xe[4] = {pb[p].x, pb[p].y, pb[p].z, pb[p].w};
#pragma unroll
      for (int e = 0; e < 4; ++e) {
        const u16 h = f2bf(xe[e]);
        ph[p].u[e] = h;
        pl[p].u[e] = f2bf(xe[e] - bf2f(h));
      }
    }

    __syncthreads();   // previous iter's frag reads done before overwrite
    *(uint4*)&Ah_s[ar * 40 + ak]     = pa0;
    *(uint4*)&Ah_s[ar * 40 + ak + 8] = pa1;
    *(uint4*)&Al_s[ar * 40 + ak]     = pl0;
    *(uint4*)&Al_s[ar * 40 + ak + 8] = pl1;
#pragma unroll
    for (int p = 0; p < 4; ++p) {
      *(uint2*)&Bh_s[(br + p * 32) * 40 + bk] = ph[p].v;
      *(uint2*)&Bl_s[(br + p * 32) * 40 + bk] = pl[p].v;
    }
    __syncthreads();

    // prefetch next tile while MFMAs run
    if (k0 + 32 < K) {
      const int kn = k0 + 32;
      pa0 = *(const uint4*)(gAh + kn);
      pa1 = *(const uint4*)(gAh + kn + 8);
      pl0 = *(const uint4*)(gAl + kn);
      pl1 = *(const uint4*)(gAl + kn + 8);
#pragma unroll
      for (int p = 0; p < 4; ++p)
        pb[p] = *(const float4*)(gB + (size_t)(p * 32) * K + kn);
    }

    // fragments + 48 MFMA per wave
    bf16x8 fah[4], fal[4];
#pragma unroll
    for (int i = 0; i < 4; ++i) {
      fah[i] = *(const bf16x8*)&Ah_s[abase + i * 640];
      fal[i] = *(const bf16x8*)&Al_s[abase + i * 640];
    }
#pragma unroll
    for (int j = 0; j < 4; ++j) {
      const bf16x8 fbh = *(const bf16x8*)&Bh_s[bbase + j * 640];
      const bf16x8 fbl = *(const bf16x8*)&Bl_s[bbase + j * 640];
#pragma unroll
      for (int i = 0; i < 4; ++i) {
        acc[i][j] = __builtin_amdgcn_mfma_f32_16x16x32_bf16(fah[i], fbh, acc[i][j], 0, 0, 0);
        acc[i][j] = __builtin_amdgcn_mfma_f32_16x16x32_bf16(fah[i], fbl, acc[i][j], 0, 0, 0);
        acc[i][j] = __builtin_amdgcn_mfma_f32_16x16x32_bf16(fal[i], fbh, acc[i][j], 0, 0, 0);
      }
    }
  }

  // epilogue: C/D layout col = lane&15, row = (lane>>4)*4 + reg (m89-verified)
#pragma unroll
  for (int j = 0; j < 4; ++j) {
    const int col = bn + wn * 64 + j * 16 + r16;
    const float bv = bias[col];
#pragma unroll
    for (int i = 0; i < 4; ++i) {
      const int row0 = bm + wm * 64 + i * 16 + kj * 4;
#pragma unroll
      for (int q = 0; q < 4; ++q)
        C[(size_t)(row0 + q) * N + col] = acc[i][j][q] + bv;
    }
  }
}

// ---------------------------------------------------------------------------
// K2: per-step gates accumulate:  preact_t[b][j] += sum_k hx[b][k]*W_hh[j][k]
// ---------------------------------------------------------------------------
__global__ __launch_bounds__(256) void lstm_gates(const float* __restrict__ hx,
                                                  const float* __restrict__ W_hh,
                                                  float* __restrict__ preact_t) {
  __shared__ __align__(16) float hs[128 * 36];  // hs[k*36 + b], padded
  const int tid = threadIdx.x;
  const int k0 = blockIdx.x * 128;
  const int h0 = blockIdx.y * 32;

  for (int i = tid; i < 32 * 128; i += 256) {
    int b = i >> 7, k = i & 127;
    hs[k * 36 + b] = hx[b * H_ + k0 + k];
  }
  __syncthreads();

  const int p = tid >> 2;          // 0..63
  const int bo = (tid & 3) * 8;    // 0,8,16,24
  const int r0 = p, r1 = p + 64;
  const int j0 = (r0 >> 5) * H_ + h0 + (r0 & 31);
  const int j1 = (r1 >> 5) * H_ + h0 + (r1 & 31);
  const float* w0p = W_hh + (size_t)j0 * H_ + k0;
  const float* w1p = W_hh + (size_t)j1 * H_ + k0;

  float acc0[8], acc1[8];
#pragma unroll
  for (int i = 0; i < 8; ++i) { acc0[i] = 0.f; acc1[i] = 0.f; }

#pragma unroll 4
  for (int kk = 0; kk < 128; kk += 4) {
    const float4 w0 = *(const float4*)(w0p + kk);
    const float4 w1 = *(const float4*)(w1p + kk);
    const float wa[4] = {w0.x, w0.y, w0.z, w0.w};
    const float wb[4] = {w1.x, w1.y, w1.z, w1.w};
#pragma unroll
    for (int i = 0; i < 4; ++i) {
      const float4 h0v = *(const float4*)&hs[(kk + i) * 36 + bo];
      const float4 h1v = *(const float4*)&hs[(kk + i) * 36 + bo + 4];
      acc0[0] = fmaf(wa[i], h0v.x, acc0[0]);
      acc0[1] = fmaf(wa[i], h0v.y, acc0[1]);
      acc0[2] = fmaf(wa[i], h0v.z, acc0[2]);
      acc0[3] = fmaf(wa[i], h0v.w, acc0[3]);
      acc0[4] = fmaf(wa[i], h1v.x, acc0[4]);
      acc0[5] = fmaf(wa[i], h1v.y, acc0[5]);
      acc0[6] = fmaf(wa[i], h1v.z, acc0[6]);
      acc0[7] = fmaf(wa[i], h1v.w, acc0[7]);
      acc1[0] = fmaf(wb[i], h0v.x, acc1[0]);
      acc1[1] = fmaf(wb[i], h0v.y, acc1[1]);
      acc1[2] = fmaf(wb[i], h0v.z, acc1[2]);
      acc1[3] = fmaf(wb[i], h0v.w, acc1[3]);
      acc1[4] = fmaf(wb[i], h1v.x, acc1[4]);
      acc1[5] = fmaf(wb[i], h1v.y, acc1[5]);
      acc1[6] = fmaf(wb[i], h1v.z, acc1[6]);
      acc1[7] = fmaf(wb[i], h1v.w, acc1[7]);
    }
  }

#pragma unroll
  for (int bb = 0; bb < 8; ++bb) {
    atomicAdd(&preact_t[(bo + bb) * G4_ + j0], acc0[bb]);
    atomicAdd(&preact_t[(bo + bb) * G4_ + j1], acc1[bb]);
  }
}

// ---------------------------------------------------------------------------
// K3: cell update. 32768 threads = (b,h). Also emits hn as bf16 hi/lo (the
// pre-split A operand of the final MFMA GEMM) — free: we touch every h anyway.
// ---------------------------------------------------------------------------
__device__ __forceinline__ float sigf(float x) { return 1.0f / (1.0f + expf(-x)); }

__global__ __launch_bounds__(256) void lstm_cell(const float* __restrict__ pre,
                                                 float* __restrict__ hx,
                                                 float* __restrict__ cx,
                                                 u16* __restrict__ ahi_t,
                                                 u16* __restrict__ alo_t) {
  const int tid = blockIdx.x * 256 + threadIdx.x;  // 0..32767
  const int b = tid >> 10, h = tid & 1023;
  const float gi = pre[b * G4_ + h];
  const float gf = pre[b * G4_ + H_ + h];
  const float gg = pre[b * G4_ + 2 * H_ + h];
  const float go = pre[b * G4_ + 3 * H_ + h];
  const float c = cx[tid];
  const float cn = sigf(gf) * c + sigf(gi) * tanhf(gg);
  const float hn = sigf(go) * tanhf(cn);
  cx[tid] = cn;
  hx[tid] = hn;
  const u16 hh = f2bf(hn);
  ahi_t[tid] = hh;
  alo_t[tid] = f2bf(hn - bf2f(hh));
}

// ---------------------------------------------------------------------------
// K5: argmax over V per row m; predic[b][t] = argmax_v logits[m][v], first max.
// ---------------------------------------------------------------------------
__global__ __launch_bounds__(256) void argmax_rows(const float* __restrict__ logits,
                                                   float* __restrict__ predic) {
  const int m = blockIdx.x;  // 0..2047
  const float* row = logits + (size_t)m * V_;
  const int tid = threadIdx.x;
  float bv = -3.402823466e38f;
  int bi = V_;
  for (int v = tid; v < V_; v += 256) {
    float x = row[v];
    if (x > bv) { bv = x; bi = v; }   // ascending v => first-max kept
  }
  __shared__ float sv[256];
  __shared__ int si[256];
  sv[tid] = bv; si[tid] = bi;
  __syncthreads();
  for (int s = 128; s > 0; s >>= 1) {
    if (tid < s) {
      if (sv[tid + s] > sv[tid] ||
          (sv[tid + s] == sv[tid] && si[tid + s] < si[tid])) {
        sv[tid] = sv[tid + s];
        si[tid] = si[tid + s];
      }
    }
    __syncthreads();
  }
  if (tid == 0) {
    int t = m >> 5, b = m & 31;
    predic[b * T_ + t] = (float)si[0];
  }
}

// ---------------------------------------------------------------------------
extern "C" void kernel_launch(void* const* d_in, const int* in_sizes, int n_in,
                              void* d_out, int out_size, void* d_ws, size_t ws_size,
                              hipStream_t stream) {
  const float* enc  = (const float*)d_in[0];
  const int*   gt   = (const int*)d_in[1];
  const float* emb  = (const float*)d_in[2];
  const float* W_ih = (const float*)d_in[3];
  const float* W_hh = (const float*)d_in[4];
  const float* b_ih = (const float*)d_in[5];
  const float* b_hh = (const float*)d_in[6];
  const float* W_fc = (const float*)d_in[7];
  const float* b_fc = (const float*)d_in[8];
  // d_in[9]=ssprob=1, d_in[10]=is_train=1 -> teacher forcing always.

  float* out    = (float*)d_out;
  float* logits = out;                          // [2048][32000]
  float* predic = out + (size_t)M_ * V_;        // [32][64]

  // scratch inside d_out (dead before final GEMM overwrites it):
  float* Xbuf   = out;                          // 3,145,728 floats
  float* preact = out + 4194304;                // 8,388,608 floats

  float* ws     = (float*)d_ws;
  float* hx     = ws;                           // 32768
  float* cx     = ws + 32768;                   // 32768
  float* bsum   = ws + 65536;                   // 4096
  // bf16 hi/lo of hx_all, in the slot previously holding fp32 hx_all:
  // Ahi: [2048][1024] u16 (4 MB), Alo: same. Total = old 2M-float footprint.
  u16* Ahi      = (u16*)(ws + 131072);
  u16* Alo      = Ahi + (size_t)M_ * H_;        // ends at ws + 2,228,224 floats

  hipMemsetAsync(hx, 0, 32768 * sizeof(float), stream);
  hipMemsetAsync(cx, 0, 32768 * sizeof(float), stream);

  build_x<<<dim3(M_, 6), 256, 0, stream>>>(enc, gt, emb, Xbuf);
  bias_sum_k<<<16, 256, 0, stream>>>(b_ih, b_hh, bsum);

  // preact[2048][4096] = X @ W_ih^T + (b_ih + b_hh)   (fp32 path, ~290 us)
  gemm_abt<<<dim3(G4_ / 128, M_ / 128), 256, 0, stream>>>(
      Xbuf, W_ih, bsum, preact, M_, G4_, ED_);

  for (int t = 0; t < T_; ++t) {
    float* pre_t = preact + (size_t)t * B_ * G4_;
    lstm_gates<<<dim3(8, 32), 256, 0, stream>>>(hx, W_hh, pre_t);
    lstm_cell<<<128, 256, 0, stream>>>(pre_t, hx, cx,
                                       Ahi + (size_t)t * B_ * H_,
                                       Alo + (size_t)t * B_ * H_);
  }

  // logits[2048][32000] = (Ahi+Alo) @ W_fc^T + b_fc   (bf16x3 MFMA)
  gemm_bf16x3<<<dim3(V_ / 128, M_ / 128), 256, 0, stream>>>(
      Ahi, Alo, W_fc, b_fc, logits, M_, V_, H_);

  argmax_rows<<<M_, 256, 0, stream>>>(logits, predic);
}